// Round 7
// baseline (669.477 us; speedup 1.0000x reference)
//
#include <hip/hip_runtime.h>
#include <math.h>

#define MROWS 4096
#define DMODEL 256
#define DMEM 512
#define NHEAD 8
#define DHEAD 32
#define DINNER 1024
#define DOUT 240
#define TSEQ 1024
#define QKV_LD 768
#define KH_LD 512

typedef __bf16 bf16x8 __attribute__((ext_vector_type(8)));
typedef float f32x4 __attribute__((ext_vector_type(4)));

__device__ __forceinline__ ushort f2b(float f) {
    unsigned u = __builtin_bit_cast(unsigned, f);
    return (ushort)((u + 0x7FFFu + ((u >> 16) & 1u)) >> 16);
}
__device__ __forceinline__ float b2f(ushort h) {
    return __builtin_bit_cast(float, (unsigned)h << 16);
}

// ---------------------------------------------------------------------------
// bf16 MFMA GEMM.  C[M,N] = op(A[M,K] @ W[K,N]) with W transposed: Bt[N][K].
// BM=BN=32, BK=64, 128 threads (2 waves).
// ---------------------------------------------------------------------------
template <int RELU, int BIAS, int ACC, int OUTBF>
__global__ __launch_bounds__(128) void gemm_bf16(
    const ushort* __restrict__ A, int lda,
    const ushort* __restrict__ Bt, int ldb,
    const float* __restrict__ bias,
    float* __restrict__ Cf, ushort* __restrict__ Cb,
    int N, int K, float scale)
{
    __shared__ __align__(16) ushort As[32][88];
    __shared__ __align__(16) ushort Bs[32][88];
    const int tid = threadIdx.x;
    const int m0 = blockIdx.y * 32;
    const int n0 = blockIdx.x * 32;
    const int w = tid >> 6;
    const int lane = tid & 63;
    const int lr = lane & 15;
    const int lg = lane >> 4;

    const int r0 = tid >> 3;
    const int kc0 = (tid & 7) * 8;

    f32x4 acc[2] = {};

    for (int k0 = 0; k0 < K; k0 += 64) {
        const int4 av0 = *(const int4*)&A[(size_t)(m0 + r0) * lda + k0 + kc0];
        const int4 av1 = *(const int4*)&A[(size_t)(m0 + r0 + 16) * lda + k0 + kc0];
        int4 bv0 = make_int4(0, 0, 0, 0), bv1 = make_int4(0, 0, 0, 0);
        if (n0 + r0 < N)      bv0 = *(const int4*)&Bt[(size_t)(n0 + r0) * ldb + k0 + kc0];
        if (n0 + r0 + 16 < N) bv1 = *(const int4*)&Bt[(size_t)(n0 + r0 + 16) * ldb + k0 + kc0];
        __syncthreads();
        *(int4*)&As[r0][kc0]      = av0;
        *(int4*)&As[r0 + 16][kc0] = av1;
        *(int4*)&Bs[r0][kc0]      = bv0;
        *(int4*)&Bs[r0 + 16][kc0] = bv1;
        __syncthreads();
#pragma unroll
        for (int h = 0; h < 2; h++) {
            const bf16x8 bfr = *reinterpret_cast<const bf16x8*>(&Bs[w * 16 + lr][h * 32 + lg * 8]);
#pragma unroll
            for (int f = 0; f < 2; f++) {
                const bf16x8 afr = *reinterpret_cast<const bf16x8*>(&As[f * 16 + lr][h * 32 + lg * 8]);
                acc[f] = __builtin_amdgcn_mfma_f32_16x16x32_bf16(afr, bfr, acc[f], 0, 0, 0);
            }
        }
    }

#pragma unroll
    for (int f = 0; f < 2; f++) {
        const int row = m0 + f * 16 + lg * 4;
        const int col = n0 + w * 16 + lr;
        if (col < N) {
            const float bv = BIAS ? bias[col] : 0.0f;
#pragma unroll
            for (int r = 0; r < 4; r++) {
                float val = acc[f][r] + bv;
                if (RELU) val = fmaxf(val, 0.0f);
                const size_t idx = (size_t)(row + r) * N + col;
                if (ACC) val += Cf[idx];
                val *= scale;
                if (OUTBF) Cb[idx] = f2b(val);
                else       Cf[idx] = val;
            }
        }
    }
}

// ---------------------------------------------------------------------------
// Fused LayerNorm + GEMM, K=256 fixed.  X fp32 [M][256] -> LN -> @ Bt[N][256]
// (+bias, relu) -> bf16 Cb or fp32 Cf.  256 threads, BM=BN=32.
// LN: 8 lanes/row (thread t: row t>>3, lanes t&7), two-pass mean/var via
// shfl_xor(1,2,4).  Whole K in LDS -> barrier-free 8-MFMA loop per wave.
// ---------------------------------------------------------------------------
template <int RELU, int OUTBF>
__global__ __launch_bounds__(256) void ln_gemm_k(
    const float* __restrict__ X,
    const ushort* __restrict__ Bt,
    const float* __restrict__ g, const float* __restrict__ bvec,
    const float* __restrict__ bias,
    float* __restrict__ Cf, ushort* __restrict__ Cb,
    int N, float eps)
{
    __shared__ __align__(16) ushort As[32][264];
    __shared__ __align__(16) ushort Bs[32][264];
    const int t = threadIdx.x;
    const int m0 = blockIdx.y * 32;
    const int n0 = blockIdx.x * 32;

    // ---- load + LN ----
    const int r = t >> 3, q = t & 7;
    float4 v[8];
    const float* xr = X + (size_t)(m0 + r) * 256;
#pragma unroll
    for (int j = 0; j < 8; j++) v[j] = *(const float4*)(xr + q * 4 + j * 32);
    float sum = 0.f;
#pragma unroll
    for (int j = 0; j < 8; j++) sum += v[j].x + v[j].y + v[j].z + v[j].w;
    sum += __shfl_xor(sum, 1); sum += __shfl_xor(sum, 2); sum += __shfl_xor(sum, 4);
    const float mean = sum * (1.0f / 256.0f);
    float s2 = 0.f;
#pragma unroll
    for (int j = 0; j < 8; j++) {
        v[j].x -= mean; v[j].y -= mean; v[j].z -= mean; v[j].w -= mean;
        s2 += v[j].x * v[j].x + v[j].y * v[j].y + v[j].z * v[j].z + v[j].w * v[j].w;
    }
    s2 += __shfl_xor(s2, 1); s2 += __shfl_xor(s2, 2); s2 += __shfl_xor(s2, 4);
    const float rstd = rsqrtf(s2 * (1.0f / 256.0f) + eps);
#pragma unroll
    for (int j = 0; j < 8; j++) {
        const float4 gv = *(const float4*)(g + q * 4 + j * 32);
        const float4 bb = *(const float4*)(bvec + q * 4 + j * 32);
        ushort4 y;
        y.x = f2b(v[j].x * rstd * gv.x + bb.x);
        y.y = f2b(v[j].y * rstd * gv.y + bb.y);
        y.z = f2b(v[j].z * rstd * gv.z + bb.z);
        y.w = f2b(v[j].w * rstd * gv.w + bb.w);
        *(ushort4*)&As[r][q * 4 + j * 32] = y;
    }

    // ---- stage full B tile [32][256] ----
    {
        const int br = t >> 3;
        const int bk = (t & 7) * 8;
#pragma unroll
        for (int k0 = 0; k0 < 256; k0 += 64) {
            int4 bv4 = make_int4(0, 0, 0, 0);
            if (n0 + br < N) bv4 = *(const int4*)&Bt[(size_t)(n0 + br) * 256 + k0 + bk];
            *(int4*)&Bs[br][k0 + bk] = bv4;
        }
    }
    __syncthreads();

    // ---- MFMA: wave w -> quadrant (fh = m half, nh = n half) ----
    const int w = t >> 6, lane = t & 63, lr = lane & 15, lg = lane >> 4;
    const int fh = w >> 1, nh = w & 1;
    f32x4 acc = {0.f, 0.f, 0.f, 0.f};
#pragma unroll
    for (int k0 = 0; k0 < 256; k0 += 32) {
        const bf16x8 afr = *(const bf16x8*)&As[fh * 16 + lr][k0 + lg * 8];
        const bf16x8 bfr = *(const bf16x8*)&Bs[nh * 16 + lr][k0 + lg * 8];
        acc = __builtin_amdgcn_mfma_f32_16x16x32_bf16(afr, bfr, acc, 0, 0, 0);
    }
    const int row = m0 + fh * 16 + lg * 4;
    const int col = n0 + nh * 16 + lr;
    if (col < N) {
        const float bb = bias[col];
#pragma unroll
        for (int rr = 0; rr < 4; rr++) {
            float val = acc[rr] + bb;
            if (RELU) val = fmaxf(val, 0.0f);
            const size_t idx = (size_t)(row + rr) * N + col;
            if (OUTBF) Cb[idx] = f2b(val);
            else       Cf[idx] = val;
        }
    }
}

// ---------------------------------------------------------------------------
// MFMA dual banded attention (unchanged from round 6, verified).
// ---------------------------------------------------------------------------
__global__ __launch_bounds__(64) void attn_mfma_k(
    const ushort* __restrict__ qkv, const ushort* __restrict__ khvh,
    ushort* __restrict__ o,
    const int* __restrict__ xbw_p, const int* __restrict__ hbw_p)
{
    __shared__ __align__(16) ushort Vt[32][40];

    const int l = threadIdx.x;
    const int c = l & 15;
    const int g = l >> 4;
    const int i0 = blockIdx.x * 16;
    const int h  = blockIdx.y;
    const int rowb = blockIdx.z * TSEQ;
    const int i = i0 + c;
    const int xbw = min(xbw_p[0], 64);
    const int hbw = min(hbw_p[0], 48);
    const float scale = 0.17677669529663687f;
    const f32x4 fz = {0.0f, 0.0f, 0.0f, 0.0f};

    const bf16x8 qf = *(const bf16x8*)(qkv + (size_t)(rowb + i) * QKV_LD + h * DHEAD + g * 8);

    f32x4 sx[5], sh[4];
#pragma unroll
    for (int t = 0; t < 5; t++) {
        int kr = i0 - 64 + t * 16 + c;
        kr = min(max(kr, 0), TSEQ - 1);
        const bf16x8 kf = *(const bf16x8*)(qkv + (size_t)(rowb + kr) * QKV_LD + 256 + h * DHEAD + g * 8);
        sx[t] = __builtin_amdgcn_mfma_f32_16x16x32_bf16(kf, qf, fz, 0, 0, 0);
    }
#pragma unroll
    for (int t = 0; t < 4; t++) {
        int kr = i0 + t * 16 + c;
        kr = min(kr, TSEQ - 1);
        const bf16x8 kf = *(const bf16x8*)(khvh + (size_t)(rowb + kr) * KH_LD + h * DHEAD + g * 8);
        sh[t] = __builtin_amdgcn_mfma_f32_16x16x32_bf16(kf, qf, fz, 0, 0, 0);
    }

    const float NEG = -3.0e38f;
    float mx = NEG, mh = NEG;
#pragma unroll
    for (int t = 0; t < 5; t++)
#pragma unroll
        for (int r = 0; r < 4; r++) {
            const int j = i0 - 64 + t * 16 + g * 4 + r;
            const bool v = (j >= i - xbw) & (j <= i) & (j >= 0);
            sx[t][r] = v ? sx[t][r] : NEG;
            mx = fmaxf(mx, sx[t][r]);
        }
#pragma unroll
    for (int t = 0; t < 4; t++)
#pragma unroll
        for (int r = 0; r < 4; r++) {
            const int j = i0 + t * 16 + g * 4 + r;
            const int dj = j - i;
            const bool v = (dj >= 0) & (dj <= hbw) & (j <= TSEQ - 1);
            sh[t][r] = v ? sh[t][r] : NEG;
            mh = fmaxf(mh, sh[t][r]);
        }
    mx = fmaxf(mx, __shfl_xor(mx, 16)); mx = fmaxf(mx, __shfl_xor(mx, 32));
    mh = fmaxf(mh, __shfl_xor(mh, 16)); mh = fmaxf(mh, __shfl_xor(mh, 32));

    float sumx = 0.0f, sumh = 0.0f;
#pragma unroll
    for (int t = 0; t < 5; t++)
#pragma unroll
        for (int r = 0; r < 4; r++) { const float e = __expf((sx[t][r] - mx) * scale); sx[t][r] = e; sumx += e; }
#pragma unroll
    for (int t = 0; t < 4; t++)
#pragma unroll
        for (int r = 0; r < 4; r++) { const float e = __expf((sh[t][r] - mh) * scale); sh[t][r] = e; sumh += e; }
    sumx += __shfl_xor(sumx, 16); sumx += __shfl_xor(sumx, 32);
    sumh += __shfl_xor(sumh, 16); sumh += __shfl_xor(sumh, 32);
    const float invx = 1.0f / sumx;
    const float invh = 1.0f / sumh;

    unsigned pkx[6][2], pkh[4][2];
#pragma unroll
    for (int t = 0; t < 5; t++) {
        pkx[t][0] = (unsigned)f2b(sx[t][0] * invx) | ((unsigned)f2b(sx[t][1] * invx) << 16);
        pkx[t][1] = (unsigned)f2b(sx[t][2] * invx) | ((unsigned)f2b(sx[t][3] * invx) << 16);
    }
    pkx[5][0] = 0; pkx[5][1] = 0;
#pragma unroll
    for (int t = 0; t < 4; t++) {
        pkh[t][0] = (unsigned)f2b(sh[t][0] * invh) | ((unsigned)f2b(sh[t][1] * invh) << 16);
        pkh[t][1] = (unsigned)f2b(sh[t][2] * invh) | ((unsigned)f2b(sh[t][3] * invh) << 16);
    }

    f32x4 acc0 = fz, acc1 = fz;
    const int src0 = ((l >> 4) & 1) * 32 + c;
    const int src1 = src0 + 16;
    const bool hiT = (g >= 2);

    const int jq  = l >> 2;
    const int dq  = l & 3;
    const int dcol = dq * 8;
    const int col1 = ((((l >> 5) + 0) ^ dq) << 3) | (jq & 7);
    const int col2 = ((((l >> 5) + 2) ^ dq) << 3) | (jq & 7);
    const int rb0 = ((g ^ ((c) >> 3)) << 3);
    const int rb1 = ((g ^ (2 + (c >> 3))) << 3);

#define PV_CHUNK(VBASE, VLD, JB, PA0, PA1, PB0, PB1)                                   \
    {                                                                                   \
        int r1 = min(max((JB) + jq, 0), TSEQ - 1);                                      \
        int r2 = min(max((JB) + 16 + jq, 0), TSEQ - 1);                                 \
        const int4 v1 = *(const int4*)((VBASE) + (size_t)(rowb + r1) * (VLD) + dcol);   \
        const int4 v2 = *(const int4*)((VBASE) + (size_t)(rowb + r2) * (VLD) + dcol);   \
        __syncthreads();                                                                \
        const ushort* u1 = (const ushort*)&v1;                                          \
        const ushort* u2 = (const ushort*)&v2;                                          \
        _Pragma("unroll")                                                               \
        for (int e = 0; e < 8; e++) { Vt[dcol + e][col1] = u1[e]; Vt[dcol + e][col2] = u2[e]; } \
        const unsigned xA0 = __shfl((int)(PA0), src0), xA1 = __shfl((int)(PA1), src0);  \
        const unsigned xA2 = __shfl((int)(PA0), src1), xA3 = __shfl((int)(PA1), src1);  \
        const unsigned xB0 = __shfl((int)(PB0), src0), xB1 = __shfl((int)(PB1), src0);  \
        const unsigned xB2 = __shfl((int)(PB0), src1), xB3 = __shfl((int)(PB1), src1);  \
        int4 au;                                                                        \
        au.x = (int)(hiT ? xB0 : xA0); au.y = (int)(hiT ? xB1 : xA1);                   \
        au.z = (int)(hiT ? xB2 : xA2); au.w = (int)(hiT ? xB3 : xA3);                   \
        const bf16x8 pf = __builtin_bit_cast(bf16x8, au);                               \
        __syncthreads();                                                                \
        const bf16x8 vf0 = *(const bf16x8*)&Vt[c][rb0];                                 \
        const bf16x8 vf1 = *(const bf16x8*)&Vt[16 + c][rb1];                            \
        acc0 = __builtin_amdgcn_mfma_f32_16x16x32_bf16(pf, vf0, acc0, 0, 0, 0);         \
        acc1 = __builtin_amdgcn_mfma_f32_16x16x32_bf16(pf, vf1, acc1, 0, 0, 0);         \
    }

    const ushort* vx = qkv + 512 + h * DHEAD;
    const ushort* vh = khvh + 256 + h * DHEAD;
    PV_CHUNK(vx, QKV_LD, i0 - 64, pkx[0][0], pkx[0][1], pkx[1][0], pkx[1][1]);
    PV_CHUNK(vx, QKV_LD, i0 - 32, pkx[2][0], pkx[2][1], pkx[3][0], pkx[3][1]);
    PV_CHUNK(vx, QKV_LD, i0,      pkx[4][0], pkx[4][1], pkx[5][0], pkx[5][1]);
    PV_CHUNK(vh, KH_LD,  i0,      pkh[0][0], pkh[0][1], pkh[1][0], pkh[1][1]);
    PV_CHUNK(vh, KH_LD,  i0 + 32, pkh[2][0], pkh[2][1], pkh[3][0], pkh[3][1]);
#undef PV_CHUNK

#pragma unroll
    for (int r = 0; r < 4; r++) {
        const size_t row = (size_t)(rowb + i0 + g * 4 + r) * DMODEL + h * DHEAD;
        o[row + c]      = f2b(acc0[r]);
        o[row + 16 + c] = f2b(acc1[r]);
    }
}

// ---------------------------------------------------------------------------
// Mega weight convert+transpose: 13 segments, one launch.
// Each segment: fp32 [K][N] (L batched) -> bf16 [N][Kd], K zero-padded.
// ---------------------------------------------------------------------------
struct WSeg {
    const float* src; ushort* dst;
    long sstride, dstride;
    int K, N, Kd, tx, tpl, start;
};
struct WcvtArgs { WSeg s[13]; };

__global__ void wcvt_k(WcvtArgs a)
{
    const int bid = blockIdx.x;
    int si = 0;
#pragma unroll
    for (int i = 1; i < 13; i++) if (bid >= a.s[i].start) si = i;
    const WSeg sg = a.s[si];
    const int lt = bid - sg.start;
    const int l = lt / sg.tpl, rem = lt % sg.tpl;
    const int k0 = (rem / sg.tx) * 32, n0 = (rem % sg.tx) * 32;
    const float* src = sg.src + (size_t)l * sg.sstride;
    ushort* dst = sg.dst + (size_t)l * sg.dstride;

    __shared__ float tbuf[32][33];
    const int tx = threadIdx.x, ty = threadIdx.y;
#pragma unroll
    for (int r = 0; r < 4; r++) {
        const int k = k0 + ty + r * 8, n = n0 + tx;
        tbuf[ty + r * 8][tx] = (k < sg.K && n < sg.N) ? src[(size_t)k * sg.N + n] : 0.0f;
    }
    __syncthreads();
#pragma unroll
    for (int r = 0; r < 4; r++) {
        const int n = n0 + ty + r * 8, k = k0 + tx;
        if (n < sg.N && k < sg.Kd) dst[(size_t)n * sg.Kd + k] = f2b(tbuf[tx][ty + r * 8]);
    }
}

// ---------------------------------------------------------------------------
// Small conversions
// ---------------------------------------------------------------------------
__global__ void cvt4_k(const float* __restrict__ s, ushort* __restrict__ d, int n4)
{
    const int i = blockIdx.x * 256 + threadIdx.x;
    if (i >= n4) return;
    const float4 v = ((const float4*)s)[i];
    ushort4 o;
    o.x = f2b(v.x); o.y = f2b(v.y); o.z = f2b(v.z); o.w = f2b(v.w);
    ((ushort4*)d)[i] = o;
}

__global__ void padcvt_k(const float* __restrict__ s, ushort* __restrict__ d)
{
    const int i = blockIdx.x * 256 + threadIdx.x;
    const int r = i >> 7, c = i & 127;
    d[i] = (c < 80) ? f2b(s[r * 80 + c]) : (ushort)0;
}

__global__ void bcat_k(const float* __restrict__ a, const float* __restrict__ b,
                       const float* __restrict__ c, float* __restrict__ dst,
                       int na, int nb, int nc, int L)
{
    const int per = na + nb + nc;
    const int i = blockIdx.x * 256 + threadIdx.x;
    if (i >= per * L) return;
    const int l = i / per, r = i % per;
    float v;
    if (r < na) v = a[l * na + r];
    else if (r < na + nb) v = b[l * nb + (r - na)];
    else v = c[l * nc + (r - na - nb)];
    dst[i] = v;
}

// ---------------------------------------------------------------------------
// Launch
// ---------------------------------------------------------------------------
extern "C" void kernel_launch(void* const* d_in, const int* in_sizes, int n_in,
                              void* d_out, int out_size, void* d_ws, size_t ws_size,
                              hipStream_t stream)
{
    const float* inp        = (const float*)d_in[0];
    const float* memory     = (const float*)d_in[1];
    const int*   xbw        = (const int*)d_in[2];
    const int*   hbw        = (const int*)d_in[3];
    const float* prenet_w0  = (const float*)d_in[5];
    const float* prenet_b0  = (const float*)d_in[6];
    const float* prenet_w1  = (const float*)d_in[7];
    const float* prenet_b1  = (const float*)d_in[8];
    const float* prenet_fcw = (const float*)d_in[9];
    const float* prenet_fcb = (const float*)d_in[10];
    const float* in_proj_w  = (const float*)d_in[11];
    const float* in_proj_b  = (const float*)d_in[12];
    const float* ln1_g      = (const float*)d_in[13];
    const float* ln1_b      = (const float*)d_in[14];
    const float* wq         = (const float*)d_in[15];
    const float* bq         = (const float*)d_in[16];
    const float* wkx        = (const float*)d_in[17];
    const float* bkx        = (const float*)d_in[18];
    const float* wvx        = (const float*)d_in[19];
    const float* bvx        = (const float*)d_in[20];
    const float* wkh        = (const float*)d_in[21];
    const float* bkh        = (const float*)d_in[22];
    const float* wvh        = (const float*)d_in[23];
    const float* bvh        = (const float*)d_in[24];
    const float* wo         = (const float*)d_in[25];
    const float* bo         = (const float*)d_in[26];
    const float* ln2_g      = (const float*)d_in[27];
    const float* ln2_b      = (const float*)d_in[28];
    const float* w1         = (const float*)d_in[29];
    const float* b1         = (const float*)d_in[30];
    const float* w2         = (const float*)d_in[31];
    const float* b2         = (const float*)d_in[32];
    const float* lnf_g      = (const float*)d_in[33];
    const float* lnf_b      = (const float*)d_in[34];
    const float* out_w      = (const float*)d_in[35];
    const float* out_b      = (const float*)d_in[36];

    char* base = (char*)d_ws;
    const size_t MB = 1u << 20;
    float*  x    = (float*)(base);                 //  0: 4 MiB fp32 residual
    ushort* qkv  = (ushort*)(base + 6 * MB);       //  6: 6 MiB [4096][768]
    ushort* khvh = (ushort*)(base + 12 * MB);      // 12: 4 MiB [4096][512]
    ushort* ob   = (ushort*)(base + 16 * MB);      // 16: 2 MiB
    ushort* memb = (ushort*)(base + 18 * MB);      // 18: 4 MiB [4096][512]
    ushort* f1b  = qkv;                            // FFN hidden 8 MiB overlays qkv+khvh
    ushort* h0b  = qkv;                            // prenet overlays
    ushort* h1b  = (ushort*)(base + 8 * MB);
    ushort* hb   = (ushort*)(base + 12 * MB);
    ushort* inpb = ob;

    size_t off = 22 * MB;
    ushort* w0t   = (ushort*)(base + off); off += (size_t)256 * 128 * 2;
    ushort* w1pt  = (ushort*)(base + off); off += (size_t)256 * 256 * 2;
    ushort* fct   = (ushort*)(base + off); off += (size_t)256 * 256 * 2;
    ushort* ipjt  = (ushort*)(base + off); off += (size_t)256 * 768 * 2;
    ushort* qkvt  = (ushort*)(base + off); off += (size_t)6 * 768 * 256 * 2;
    ushort* khvht = (ushort*)(base + off); off += (size_t)6 * 512 * 512 * 2;
    ushort* wot   = (ushort*)(base + off); off += (size_t)6 * 256 * 256 * 2;
    ushort* w1t   = (ushort*)(base + off); off += (size_t)6 * 1024 * 256 * 2;
    ushort* w2t   = (ushort*)(base + off); off += (size_t)6 * 256 * 1024 * 2;
    ushort* owt   = (ushort*)(base + off); off += (size_t)240 * 256 * 2;
    float*  bqkv  = (float*)(base + off);  off += (size_t)6 * 768 * 4;
    float*  bkhvh = (float*)(base + off);  off += (size_t)6 * 512 * 4;

    // ---- one-launch weight conversion ----
    WcvtArgs wa;
    {
        auto seg = [](const float* src, ushort* dst, int K, int N, int Kd,
                      long ss, long ds, int L) {
            WSeg s; s.src = src; s.dst = dst; s.K = K; s.N = N; s.Kd = Kd;
            s.sstride = ss; s.dstride = ds;
            s.tx = (N + 31) / 32;
            s.tpl = s.tx * ((Kd + 31) / 32);
            s.start = 0; (void)L; return s;
        };
        wa.s[0]  = seg(prenet_w0, w0t,  80,  256, 128, 0, 0, 1);
        wa.s[1]  = seg(prenet_w1, w1pt, 256, 256, 256, 0, 0, 1);
        wa.s[2]  = seg(prenet_fcw, fct, 256, 256, 256, 0, 0, 1);
        wa.s[3]  = seg(in_proj_w, ipjt, 768, 256, 768, 0, 0, 1);
        wa.s[4]  = seg(wq,  qkvt,           256, 256,  256, 65536, 196608, 6);
        wa.s[5]  = seg(wkx, qkvt + 65536,   256, 256,  256, 65536, 196608, 6);
        wa.s[6]  = seg(wvx, qkvt + 131072,  256, 256,  256, 65536, 196608, 6);
        wa.s[7]  = seg(wkh, khvht,          512, 256,  512, 131072, 262144, 6);
        wa.s[8]  = seg(wvh, khvht + 131072, 512, 256,  512, 131072, 262144, 6);
        wa.s[9]  = seg(wo,  wot,            256, 256,  256, 65536, 65536, 6);
        wa.s[10] = seg(w1,  w1t,            256, 1024, 256, 262144, 262144, 6);
        wa.s[11] = seg(w2,  w2t,            1024, 256, 1024, 262144, 262144, 6);
        wa.s[12] = seg(out_w, owt,          256, 240,  256, 0, 0, 1);
        const int Ls[13] = {1,1,1,1,6,6,6,6,6,6,6,6,1};
        int start = 0;
        for (int i = 0; i < 13; i++) {
            wa.s[i].start = start;
            start += wa.s[i].tpl * Ls[i];
        }
        wcvt_k<<<start, dim3(32, 8), 0, stream>>>(wa);
    }
    cvt4_k<<<2048, 256, 0, stream>>>(memory, memb, (MROWS * DMEM) / 4);
    padcvt_k<<<2048, 256, 0, stream>>>(inp, inpb);
    bcat_k<<<18, 256, 0, stream>>>(bq, bkx, bvx, bqkv, 256, 256, 256, 6);
    bcat_k<<<12, 256, 0, stream>>>(bkh, bvh, bvh, bkhvh, 256, 256, 0, 6);

#define GEMM(RELU, BIAS, ACC, OUTBF, A, lda, Bt, ldb, bias_, Cf, Cb, N, K, sc) \
    gemm_bf16<RELU, BIAS, ACC, OUTBF><<<dim3(((N) + 31) / 32, MROWS / 32), 128, 0, stream>>>( \
        A, lda, Bt, ldb, bias_, Cf, Cb, N, K, sc)
#define LNGEMM(RELU, OUTBF, X_, Bt, g_, b_, bias_, Cf, Cb, N, eps) \
    ln_gemm_k<RELU, OUTBF><<<dim3(((N) + 31) / 32, MROWS / 32), 256, 0, stream>>>( \
        X_, Bt, g_, b_, bias_, Cf, Cb, N, eps)

    // ---- prenet ----
    GEMM(1, 1, 0, 1, inpb, 128, w0t, 128, prenet_b0, nullptr, h0b, 256, 128, 1.0f);
    GEMM(1, 1, 0, 1, h0b, 256, w1pt, 256, prenet_b1, nullptr, h1b, 256, 256, 1.0f);
    GEMM(0, 1, 0, 1, h1b, 256, fct, 256, prenet_fcb, nullptr, hb, 256, 256, 1.0f);

    // ---- in_proj: x = (mem@Wtop + h@Wbot + b) * 16 ----
    GEMM(0, 0, 0, 0, memb, 512, ipjt, 768, nullptr, x, nullptr, 256, 512, 1.0f);
    GEMM(0, 1, 1, 0, hb, 256, ipjt + 512, 768, in_proj_b, x, nullptr, 256, 256, 16.0f);

    // ---- layers ----
    for (int l = 0; l < 6; l++) {
        const size_t bs = (size_t)l * 256;

        LNGEMM(0, 1, x, qkvt + (size_t)l * 196608, ln1_g + bs, ln1_b + bs,
               bqkv + (size_t)l * 768, nullptr, qkv, 768, 1e-5f);
        GEMM(0, 1, 0, 1, memb, 512, khvht + (size_t)l * 262144, 512, bkhvh + (size_t)l * 512,
             nullptr, khvh, 512, 512, 1.0f);

        attn_mfma_k<<<dim3(TSEQ / 16, NHEAD, 4), 64, 0, stream>>>(qkv, khvh, ob, xbw, hbw);

        GEMM(0, 1, 1, 0, ob, 256, wot + (size_t)l * 65536, 256, bo + bs, x, nullptr, 256, 256, 1.0f);

        LNGEMM(1, 1, x, w1t + (size_t)l * 262144, ln2_g + bs, ln2_b + bs,
               b1 + (size_t)l * 1024, nullptr, f1b, 1024, 1e-5f);
        GEMM(0, 1, 1, 0, f1b, 1024, w2t + (size_t)l * 262144, 1024, b2 + bs, x, nullptr, 256, 1024, 1.0f);
    }

    // ---- final fused LN + out proj (fp32 out) ----
    LNGEMM(0, 0, x, owt, lnf_g, lnf_b, out_b, (float*)d_out, nullptr, 240, 1e-6f);
#undef GEMM
#undef LNGEMM
}

// Round 8
// 612.492 us; speedup vs baseline: 1.0930x; 1.0930x over previous
//
#include <hip/hip_runtime.h>
#include <math.h>

#define MROWS 4096
#define DMODEL 256
#define NHEAD 8
#define DHEAD 32
#define TSEQ 1024
#define QKV_LD 768

typedef __bf16 bf16x8 __attribute__((ext_vector_type(8)));
typedef float f32x4 __attribute__((ext_vector_type(4)));

__device__ __forceinline__ ushort f2b(float f) {
    unsigned u = __builtin_bit_cast(unsigned, f);
    return (ushort)((u + 0x7FFFu + ((u >> 16) & 1u)) >> 16);
}

// ---------------------------------------------------------------------------
// bf16 MFMA GEMM, BM=BN=64, BK=64, 256 threads (4 waves, 32x32 quadrant each).
// C[M,N] = op(A[M,K] @ W) with W transposed: Bt[N][K]. ldc = output row stride.
// ---------------------------------------------------------------------------
template <int RELU, int BIAS, int ACC, int OUTBF>
__global__ __launch_bounds__(256) void gemm64(
    const ushort* __restrict__ A, int lda,
    const ushort* __restrict__ Bt, int ldb,
    const float* __restrict__ bias,
    float* __restrict__ Cf, ushort* __restrict__ Cb,
    int N, int K, int ldc, float scale)
{
    __shared__ __align__(16) ushort As[64][72];
    __shared__ __align__(16) ushort Bs[64][72];
    const int t = threadIdx.x;
    const int m0 = blockIdx.y * 64;
    const int n0 = blockIdx.x * 64;
    const int w = t >> 6, lane = t & 63, lr = lane & 15, lg = lane >> 4;
    const int wm = w >> 1, wn = w & 1;

    const int r0 = t >> 2;            // staging row 0..63
    const int kc0 = (t & 3) * 16;     // staging k offset 0,16,32,48

    f32x4 acc[2][2] = {};

    for (int k0 = 0; k0 < K; k0 += 64) {
        const int4 a0 = *(const int4*)&A[(size_t)(m0 + r0) * lda + k0 + kc0];
        const int4 a1 = *(const int4*)&A[(size_t)(m0 + r0) * lda + k0 + kc0 + 8];
        int4 b0 = make_int4(0, 0, 0, 0), b1 = make_int4(0, 0, 0, 0);
        if (n0 + r0 < N) {
            b0 = *(const int4*)&Bt[(size_t)(n0 + r0) * ldb + k0 + kc0];
            b1 = *(const int4*)&Bt[(size_t)(n0 + r0) * ldb + k0 + kc0 + 8];
        }
        __syncthreads();
        *(int4*)&As[r0][kc0]     = a0;
        *(int4*)&As[r0][kc0 + 8] = a1;
        *(int4*)&Bs[r0][kc0]     = b0;
        *(int4*)&Bs[r0][kc0 + 8] = b1;
        __syncthreads();
#pragma unroll
        for (int kh = 0; kh < 2; kh++) {
            const bf16x8 af0 = *(const bf16x8*)&As[wm * 32 + lr][kh * 32 + lg * 8];
            const bf16x8 af1 = *(const bf16x8*)&As[wm * 32 + 16 + lr][kh * 32 + lg * 8];
            const bf16x8 bf0 = *(const bf16x8*)&Bs[wn * 32 + lr][kh * 32 + lg * 8];
            const bf16x8 bf1 = *(const bf16x8*)&Bs[wn * 32 + 16 + lr][kh * 32 + lg * 8];
            acc[0][0] = __builtin_amdgcn_mfma_f32_16x16x32_bf16(af0, bf0, acc[0][0], 0, 0, 0);
            acc[0][1] = __builtin_amdgcn_mfma_f32_16x16x32_bf16(af0, bf1, acc[0][1], 0, 0, 0);
            acc[1][0] = __builtin_amdgcn_mfma_f32_16x16x32_bf16(af1, bf0, acc[1][0], 0, 0, 0);
            acc[1][1] = __builtin_amdgcn_mfma_f32_16x16x32_bf16(af1, bf1, acc[1][1], 0, 0, 0);
        }
    }

#pragma unroll
    for (int mf = 0; mf < 2; mf++) {
        const int row = m0 + wm * 32 + mf * 16 + lg * 4;
#pragma unroll
        for (int nf = 0; nf < 2; nf++) {
            const int col = n0 + wn * 32 + nf * 16 + lr;
            if (col < N) {
                const float bb = BIAS ? bias[col] : 0.0f;
#pragma unroll
                for (int rr = 0; rr < 4; rr++) {
                    float val = acc[mf][nf][rr] + bb;
                    if (RELU) val = fmaxf(val, 0.0f);
                    const size_t idx = (size_t)(row + rr) * ldc + col;
                    if (ACC) val += Cf[idx];
                    val *= scale;
                    if (OUTBF) Cb[idx] = f2b(val);
                    else       Cf[idx] = val;
                }
            }
        }
    }
}

// ---------------------------------------------------------------------------
// Fused LayerNorm + GEMM, K=256 fixed, BM=BN=64, 256 threads.
// LN: 4 lanes/row (64 f32 each), two-pass via shfl_xor(1,2); normalized bf16
// to As[64][264]; full B tile to Bs; one barrier; 32 MFMAs/wave.
// ---------------------------------------------------------------------------
template <int RELU, int OUTBF>
__global__ __launch_bounds__(256) void lngemm64(
    const float* __restrict__ X,
    const ushort* __restrict__ Bt,
    const float* __restrict__ g, const float* __restrict__ bvec,
    const float* __restrict__ bias,
    float* __restrict__ Cf, ushort* __restrict__ Cb,
    int N, int ldc, float eps)
{
    __shared__ __align__(16) ushort As[64][264];
    __shared__ __align__(16) ushort Bs[64][264];
    const int t = threadIdx.x;
    const int m0 = blockIdx.y * 64;
    const int n0 = blockIdx.x * 64;

    // ---- LN: row r, 4 lanes (q), 16 float4s each ----
    {
        const int r = t >> 2, q = t & 3;
        const float* xr = X + (size_t)(m0 + r) * 256;
        float4 v[16];
#pragma unroll
        for (int j = 0; j < 16; j++) v[j] = *(const float4*)(xr + j * 16 + q * 4);
        float sum = 0.f;
#pragma unroll
        for (int j = 0; j < 16; j++) sum += v[j].x + v[j].y + v[j].z + v[j].w;
        sum += __shfl_xor(sum, 1); sum += __shfl_xor(sum, 2);
        const float mean = sum * (1.0f / 256.0f);
        float s2 = 0.f;
#pragma unroll
        for (int j = 0; j < 16; j++) {
            v[j].x -= mean; v[j].y -= mean; v[j].z -= mean; v[j].w -= mean;
            s2 += v[j].x * v[j].x + v[j].y * v[j].y + v[j].z * v[j].z + v[j].w * v[j].w;
        }
        s2 += __shfl_xor(s2, 1); s2 += __shfl_xor(s2, 2);
        const float rstd = rsqrtf(s2 * (1.0f / 256.0f) + eps);
#pragma unroll
        for (int j = 0; j < 16; j++) {
            const float4 gv = *(const float4*)(g + j * 16 + q * 4);
            const float4 bb = *(const float4*)(bvec + j * 16 + q * 4);
            ushort4 y;
            y.x = f2b(v[j].x * rstd * gv.x + bb.x);
            y.y = f2b(v[j].y * rstd * gv.y + bb.y);
            y.z = f2b(v[j].z * rstd * gv.z + bb.z);
            y.w = f2b(v[j].w * rstd * gv.w + bb.w);
            *(ushort4*)&As[r][j * 16 + q * 4] = y;
        }
    }

    // ---- stage full B tile [64][256] ----
    {
        const int br = t >> 2;
        const bool ok = (n0 + br < N);
#pragma unroll
        for (int u = 0; u < 8; u++) {
            const int e = (t & 3) * 8 + u * 32;
            int4 bv4 = make_int4(0, 0, 0, 0);
            if (ok) bv4 = *(const int4*)&Bt[(size_t)(n0 + br) * 256 + e];
            *(int4*)&Bs[br][e] = bv4;
        }
    }
    __syncthreads();

    // ---- MFMA ----
    const int w = t >> 6, lane = t & 63, lr = lane & 15, lg = lane >> 4;
    const int wm = w >> 1, wn = w & 1;
    f32x4 acc[2][2] = {};
#pragma unroll
    for (int ks = 0; ks < 8; ks++) {
        const bf16x8 af0 = *(const bf16x8*)&As[wm * 32 + lr][ks * 32 + lg * 8];
        const bf16x8 af1 = *(const bf16x8*)&As[wm * 32 + 16 + lr][ks * 32 + lg * 8];
        const bf16x8 bf0 = *(const bf16x8*)&Bs[wn * 32 + lr][ks * 32 + lg * 8];
        const bf16x8 bf1 = *(const bf16x8*)&Bs[wn * 32 + 16 + lr][ks * 32 + lg * 8];
        acc[0][0] = __builtin_amdgcn_mfma_f32_16x16x32_bf16(af0, bf0, acc[0][0], 0, 0, 0);
        acc[0][1] = __builtin_amdgcn_mfma_f32_16x16x32_bf16(af0, bf1, acc[0][1], 0, 0, 0);
        acc[1][0] = __builtin_amdgcn_mfma_f32_16x16x32_bf16(af1, bf0, acc[1][0], 0, 0, 0);
        acc[1][1] = __builtin_amdgcn_mfma_f32_16x16x32_bf16(af1, bf1, acc[1][1], 0, 0, 0);
    }

#pragma unroll
    for (int mf = 0; mf < 2; mf++) {
        const int row = m0 + wm * 32 + mf * 16 + lg * 4;
#pragma unroll
        for (int nf = 0; nf < 2; nf++) {
            const int col = n0 + wn * 32 + nf * 16 + lr;
            if (col < N) {
                const float bb = bias[col];
#pragma unroll
                for (int rr = 0; rr < 4; rr++) {
                    float val = acc[mf][nf][rr] + bb;
                    if (RELU) val = fmaxf(val, 0.0f);
                    const size_t idx = (size_t)(row + rr) * ldc + col;
                    if (OUTBF) Cb[idx] = f2b(val);
                    else       Cf[idx] = val;
                }
            }
        }
    }
}

// ---------------------------------------------------------------------------
// MFMA dual banded attention (verified r6 structure; khvh now strided).
// ---------------------------------------------------------------------------
__global__ __launch_bounds__(64) void attn_mfma_k(
    const ushort* __restrict__ qkv, const ushort* __restrict__ khvh, int kld,
    ushort* __restrict__ o,
    const int* __restrict__ xbw_p, const int* __restrict__ hbw_p)
{
    __shared__ __align__(16) ushort Vt[32][40];

    const int l = threadIdx.x;
    const int c = l & 15;
    const int g = l >> 4;
    const int i0 = blockIdx.x * 16;
    const int h  = blockIdx.y;
    const int rowb = blockIdx.z * TSEQ;
    const int i = i0 + c;
    const int xbw = min(xbw_p[0], 64);
    const int hbw = min(hbw_p[0], 48);
    const float scale = 0.17677669529663687f;
    const f32x4 fz = {0.0f, 0.0f, 0.0f, 0.0f};

    const bf16x8 qf = *(const bf16x8*)(qkv + (size_t)(rowb + i) * QKV_LD + h * DHEAD + g * 8);

    f32x4 sx[5], sh[4];
#pragma unroll
    for (int t = 0; t < 5; t++) {
        int kr = i0 - 64 + t * 16 + c;
        kr = min(max(kr, 0), TSEQ - 1);
        const bf16x8 kf = *(const bf16x8*)(qkv + (size_t)(rowb + kr) * QKV_LD + 256 + h * DHEAD + g * 8);
        sx[t] = __builtin_amdgcn_mfma_f32_16x16x32_bf16(kf, qf, fz, 0, 0, 0);
    }
#pragma unroll
    for (int t = 0; t < 4; t++) {
        int kr = i0 + t * 16 + c;
        kr = min(kr, TSEQ - 1);
        const bf16x8 kf = *(const bf16x8*)(khvh + (size_t)(rowb + kr) * kld + h * DHEAD + g * 8);
        sh[t] = __builtin_amdgcn_mfma_f32_16x16x32_bf16(kf, qf, fz, 0, 0, 0);
    }

    const float NEG = -3.0e38f;
    float mx = NEG, mh = NEG;
#pragma unroll
    for (int t = 0; t < 5; t++)
#pragma unroll
        for (int r = 0; r < 4; r++) {
            const int j = i0 - 64 + t * 16 + g * 4 + r;
            const bool v = (j >= i - xbw) & (j <= i) & (j >= 0);
            sx[t][r] = v ? sx[t][r] : NEG;
            mx = fmaxf(mx, sx[t][r]);
        }
#pragma unroll
    for (int t = 0; t < 4; t++)
#pragma unroll
        for (int r = 0; r < 4; r++) {
            const int j = i0 + t * 16 + g * 4 + r;
            const int dj = j - i;
            const bool v = (dj >= 0) & (dj <= hbw) & (j <= TSEQ - 1);
            sh[t][r] = v ? sh[t][r] : NEG;
            mh = fmaxf(mh, sh[t][r]);
        }
    mx = fmaxf(mx, __shfl_xor(mx, 16)); mx = fmaxf(mx, __shfl_xor(mx, 32));
    mh = fmaxf(mh, __shfl_xor(mh, 16)); mh = fmaxf(mh, __shfl_xor(mh, 32));

    float sumx = 0.0f, sumh = 0.0f;
#pragma unroll
    for (int t = 0; t < 5; t++)
#pragma unroll
        for (int r = 0; r < 4; r++) { const float e = __expf((sx[t][r] - mx) * scale); sx[t][r] = e; sumx += e; }
#pragma unroll
    for (int t = 0; t < 4; t++)
#pragma unroll
        for (int r = 0; r < 4; r++) { const float e = __expf((sh[t][r] - mh) * scale); sh[t][r] = e; sumh += e; }
    sumx += __shfl_xor(sumx, 16); sumx += __shfl_xor(sumx, 32);
    sumh += __shfl_xor(sumh, 16); sumh += __shfl_xor(sumh, 32);
    const float invx = 1.0f / sumx;
    const float invh = 1.0f / sumh;

    unsigned pkx[6][2], pkh[4][2];
#pragma unroll
    for (int t = 0; t < 5; t++) {
        pkx[t][0] = (unsigned)f2b(sx[t][0] * invx) | ((unsigned)f2b(sx[t][1] * invx) << 16);
        pkx[t][1] = (unsigned)f2b(sx[t][2] * invx) | ((unsigned)f2b(sx[t][3] * invx) << 16);
    }
    pkx[5][0] = 0; pkx[5][1] = 0;
#pragma unroll
    for (int t = 0; t < 4; t++) {
        pkh[t][0] = (unsigned)f2b(sh[t][0] * invh) | ((unsigned)f2b(sh[t][1] * invh) << 16);
        pkh[t][1] = (unsigned)f2b(sh[t][2] * invh) | ((unsigned)f2b(sh[t][3] * invh) << 16);
    }

    f32x4 acc0 = fz, acc1 = fz;
    const int src0 = ((l >> 4) & 1) * 32 + c;
    const int src1 = src0 + 16;
    const bool hiT = (g >= 2);

    const int jq  = l >> 2;
    const int dq  = l & 3;
    const int dcol = dq * 8;
    const int col1 = ((((l >> 5) + 0) ^ dq) << 3) | (jq & 7);
    const int col2 = ((((l >> 5) + 2) ^ dq) << 3) | (jq & 7);
    const int rb0 = ((g ^ ((c) >> 3)) << 3);
    const int rb1 = ((g ^ (2 + (c >> 3))) << 3);

#define PV_CHUNK(VBASE, VLD, JB, PA0, PA1, PB0, PB1)                                   \
    {                                                                                   \
        int r1 = min(max((JB) + jq, 0), TSEQ - 1);                                      \
        int r2 = min(max((JB) + 16 + jq, 0), TSEQ - 1);                                 \
        const int4 v1 = *(const int4*)((VBASE) + (size_t)(rowb + r1) * (VLD) + dcol);   \
        const int4 v2 = *(const int4*)((VBASE) + (size_t)(rowb + r2) * (VLD) + dcol);   \
        __syncthreads();                                                                \
        const ushort* u1 = (const ushort*)&v1;                                          \
        const ushort* u2 = (const ushort*)&v2;                                          \
        _Pragma("unroll")                                                               \
        for (int e = 0; e < 8; e++) { Vt[dcol + e][col1] = u1[e]; Vt[dcol + e][col2] = u2[e]; } \
        const unsigned xA0 = __shfl((int)(PA0), src0), xA1 = __shfl((int)(PA1), src0);  \
        const unsigned xA2 = __shfl((int)(PA0), src1), xA3 = __shfl((int)(PA1), src1);  \
        const unsigned xB0 = __shfl((int)(PB0), src0), xB1 = __shfl((int)(PB1), src0);  \
        const unsigned xB2 = __shfl((int)(PB0), src1), xB3 = __shfl((int)(PB1), src1);  \
        int4 au;                                                                        \
        au.x = (int)(hiT ? xB0 : xA0); au.y = (int)(hiT ? xB1 : xA1);                   \
        au.z = (int)(hiT ? xB2 : xA2); au.w = (int)(hiT ? xB3 : xA3);                   \
        const bf16x8 pf = __builtin_bit_cast(bf16x8, au);                               \
        __syncthreads();                                                                \
        const bf16x8 vf0 = *(const bf16x8*)&Vt[c][rb0];                                 \
        const bf16x8 vf1 = *(const bf16x8*)&Vt[16 + c][rb1];                            \
        acc0 = __builtin_amdgcn_mfma_f32_16x16x32_bf16(pf, vf0, acc0, 0, 0, 0);         \
        acc1 = __builtin_amdgcn_mfma_f32_16x16x32_bf16(pf, vf1, acc1, 0, 0, 0);         \
    }

    const ushort* vx = qkv + 512 + h * DHEAD;
    const ushort* vh = khvh + 256 + h * DHEAD;
    PV_CHUNK(vx, QKV_LD, i0 - 64, pkx[0][0], pkx[0][1], pkx[1][0], pkx[1][1]);
    PV_CHUNK(vx, QKV_LD, i0 - 32, pkx[2][0], pkx[2][1], pkx[3][0], pkx[3][1]);
    PV_CHUNK(vx, QKV_LD, i0,      pkx[4][0], pkx[4][1], pkx[5][0], pkx[5][1]);
    PV_CHUNK(vh, kld,    i0,      pkh[0][0], pkh[0][1], pkh[1][0], pkh[1][1]);
    PV_CHUNK(vh, kld,    i0 + 32, pkh[2][0], pkh[2][1], pkh[3][0], pkh[3][1]);
#undef PV_CHUNK

#pragma unroll
    for (int r = 0; r < 4; r++) {
        const size_t row = (size_t)(rowb + i0 + g * 4 + r) * DMODEL + h * DHEAD;
        o[row + c]      = f2b(acc0[r]);
        o[row + 16 + c] = f2b(acc1[r]);
    }
}

// ---------------------------------------------------------------------------
// Mega weight convert+transpose: 13 segments, one launch.
// ---------------------------------------------------------------------------
struct WSeg {
    const float* src; ushort* dst;
    long sstride, dstride;
    int K, N, Kd, tx, tpl, start;
};
struct WcvtArgs { WSeg s[13]; };

__global__ void wcvt_k(WcvtArgs a)
{
    const int bid = blockIdx.x;
    int si = 0;
#pragma unroll
    for (int i = 1; i < 13; i++) if (bid >= a.s[i].start) si = i;
    const WSeg sg = a.s[si];
    const int lt = bid - sg.start;
    const int l = lt / sg.tpl, rem = lt % sg.tpl;
    const int k0 = (rem / sg.tx) * 32, n0 = (rem % sg.tx) * 32;
    const float* src = sg.src + (size_t)l * sg.sstride;
    ushort* dst = sg.dst + (size_t)l * sg.dstride;

    __shared__ float tbuf[32][33];
    const int tx = threadIdx.x, ty = threadIdx.y;
#pragma unroll
    for (int r = 0; r < 4; r++) {
        const int k = k0 + ty + r * 8, n = n0 + tx;
        tbuf[ty + r * 8][tx] = (k < sg.K && n < sg.N) ? src[(size_t)k * sg.N + n] : 0.0f;
    }
    __syncthreads();
#pragma unroll
    for (int r = 0; r < 4; r++) {
        const int n = n0 + ty + r * 8, k = k0 + tx;
        if (n < sg.N && k < sg.Kd) dst[(size_t)n * sg.Kd + k] = f2b(tbuf[tx][ty + r * 8]);
    }
}

// ---------------------------------------------------------------------------
// Small conversions
// ---------------------------------------------------------------------------
// memory fp32 [4096][512] -> bf16 into cat [4096][768] cols 0..511
__global__ void cvtmem_k(const float* __restrict__ s, ushort* __restrict__ cat)
{
    const int i = blockIdx.x * 256 + threadIdx.x;   // 4096*128
    const int row = i >> 7, c4 = (i & 127) * 4;
    const float4 v = *(const float4*)(s + (size_t)row * 512 + c4);
    ushort4 o;
    o.x = f2b(v.x); o.y = f2b(v.y); o.z = f2b(v.z); o.w = f2b(v.w);
    *(ushort4*)(cat + (size_t)row * 768 + c4) = o;
}

__global__ void padcvt_k(const float* __restrict__ s, ushort* __restrict__ d)
{
    const int i = blockIdx.x * 256 + threadIdx.x;   // 4096*128
    const int r = i >> 7, c = i & 127;
    d[i] = (c < 80) ? f2b(s[r * 80 + c]) : (ushort)0;
}

__global__ void bcat_k(const float* __restrict__ a, const float* __restrict__ b,
                       const float* __restrict__ c, float* __restrict__ dst,
                       int na, int nb, int nc, int L)
{
    const int per = na + nb + nc;
    const int i = blockIdx.x * 256 + threadIdx.x;
    if (i >= per * L) return;
    const int l = i / per, r = i % per;
    float v;
    if (r < na) v = a[l * na + r];
    else if (r < na + nb) v = b[l * nb + (r - na)];
    else v = c[l * nc + (r - na - nb)];
    dst[i] = v;
}

// ---------------------------------------------------------------------------
// Launch
// ---------------------------------------------------------------------------
extern "C" void kernel_launch(void* const* d_in, const int* in_sizes, int n_in,
                              void* d_out, int out_size, void* d_ws, size_t ws_size,
                              hipStream_t stream)
{
    const float* inp        = (const float*)d_in[0];
    const float* memory     = (const float*)d_in[1];
    const int*   xbw        = (const int*)d_in[2];
    const int*   hbw        = (const int*)d_in[3];
    const float* prenet_w0  = (const float*)d_in[5];
    const float* prenet_b0  = (const float*)d_in[6];
    const float* prenet_w1  = (const float*)d_in[7];
    const float* prenet_b1  = (const float*)d_in[8];
    const float* prenet_fcw = (const float*)d_in[9];
    const float* prenet_fcb = (const float*)d_in[10];
    const float* in_proj_w  = (const float*)d_in[11];
    const float* in_proj_b  = (const float*)d_in[12];
    const float* ln1_g      = (const float*)d_in[13];
    const float* ln1_b      = (const float*)d_in[14];
    const float* wq         = (const float*)d_in[15];
    const float* bq         = (const float*)d_in[16];
    const float* wkx        = (const float*)d_in[17];
    const float* bkx        = (const float*)d_in[18];
    const float* wvx        = (const float*)d_in[19];
    const float* bvx        = (const float*)d_in[20];
    const float* wkh        = (const float*)d_in[21];
    const float* bkh        = (const float*)d_in[22];
    const float* wvh        = (const float*)d_in[23];
    const float* bvh        = (const float*)d_in[24];
    const float* wo         = (const float*)d_in[25];
    const float* bo         = (const float*)d_in[26];
    const float* ln2_g      = (const float*)d_in[27];
    const float* ln2_b      = (const float*)d_in[28];
    const float* w1         = (const float*)d_in[29];
    const float* b1         = (const float*)d_in[30];
    const float* w2         = (const float*)d_in[31];
    const float* b2         = (const float*)d_in[32];
    const float* lnf_g      = (const float*)d_in[33];
    const float* lnf_b      = (const float*)d_in[34];
    const float* out_w      = (const float*)d_in[35];
    const float* out_b      = (const float*)d_in[36];

    char* base = (char*)d_ws;
    const size_t MB = 1u << 20;
    float*  x        = (float*)(base);                 //  0: 4 MiB fp32 residual
    ushort* cat      = (ushort*)(base + 4 * MB);       //  4: 6 MiB [4096][768] = mem|h
    ushort* qkv      = (ushort*)(base + 10 * MB);      // 10: 6 MiB [4096][768]
    ushort* ob       = (ushort*)(base + 16 * MB);      // 16: 2 MiB
    ushort* f1b      = (ushort*)(base + 18 * MB);      // 18: 8 MiB [4096][1024]
    ushort* khvh_all = (ushort*)(base + 26 * MB);      // 26: 24 MiB [4096][3072]
    ushort* h0b      = (ushort*)(base + 50 * MB);      // 50: 2 MiB
    ushort* h1b      = (ushort*)(base + 52 * MB);      // 52: 2 MiB
    ushort* inpb     = (ushort*)(base + 54 * MB);      // 54: 1 MiB [4096][128]

    size_t off = 56 * MB;
    ushort* w0t   = (ushort*)(base + off); off += (size_t)256 * 128 * 2;
    ushort* w1pt  = (ushort*)(base + off); off += (size_t)256 * 256 * 2;
    ushort* fct   = (ushort*)(base + off); off += (size_t)256 * 256 * 2;
    ushort* ipjt  = (ushort*)(base + off); off += (size_t)256 * 768 * 2;
    ushort* qkvt  = (ushort*)(base + off); off += (size_t)6 * 768 * 256 * 2;
    ushort* khvht = (ushort*)(base + off); off += (size_t)6 * 512 * 512 * 2;   // [3072][512]
    ushort* wot   = (ushort*)(base + off); off += (size_t)6 * 256 * 256 * 2;
    ushort* w1t   = (ushort*)(base + off); off += (size_t)6 * 1024 * 256 * 2;
    ushort* w2t   = (ushort*)(base + off); off += (size_t)6 * 256 * 1024 * 2;
    ushort* owt   = (ushort*)(base + off); off += (size_t)240 * 256 * 2;
    float*  bqkv  = (float*)(base + off);  off += (size_t)6 * 768 * 4;
    float*  bkhvh = (float*)(base + off);  off += (size_t)6 * 512 * 4;         // 3072 floats

    // ---- one-launch weight conversion ----
    WcvtArgs wa;
    {
        auto seg = [](const float* src, ushort* dst, int K, int N, int Kd,
                      long ss, long ds) {
            WSeg s; s.src = src; s.dst = dst; s.K = K; s.N = N; s.Kd = Kd;
            s.sstride = ss; s.dstride = ds;
            s.tx = (N + 31) / 32;
            s.tpl = s.tx * ((Kd + 31) / 32);
            s.start = 0; return s;
        };
        wa.s[0]  = seg(prenet_w0, w0t,  80,  256, 128, 0, 0);
        wa.s[1]  = seg(prenet_w1, w1pt, 256, 256, 256, 0, 0);
        wa.s[2]  = seg(prenet_fcw, fct, 256, 256, 256, 0, 0);
        wa.s[3]  = seg(in_proj_w, ipjt, 768, 256, 768, 0, 0);
        wa.s[4]  = seg(wq,  qkvt,           256, 256,  256, 65536, 196608);
        wa.s[5]  = seg(wkx, qkvt + 65536,   256, 256,  256, 65536, 196608);
        wa.s[6]  = seg(wvx, qkvt + 131072,  256, 256,  256, 65536, 196608);
        wa.s[7]  = seg(wkh, khvht,          512, 256,  512, 131072, 262144);
        wa.s[8]  = seg(wvh, khvht + 131072, 512, 256,  512, 131072, 262144);
        wa.s[9]  = seg(wo,  wot,            256, 256,  256, 65536, 65536);
        wa.s[10] = seg(w1,  w1t,            256, 1024, 256, 262144, 262144);
        wa.s[11] = seg(w2,  w2t,            1024, 256, 1024, 262144, 262144);
        wa.s[12] = seg(out_w, owt,          256, 240,  256, 0, 0);
        const int Ls[13] = {1,1,1,1,6,6,6,6,6,6,6,6,1};
        int start = 0;
        for (int i = 0; i < 13; i++) {
            wa.s[i].start = start;
            start += wa.s[i].tpl * Ls[i];
        }
        wcvt_k<<<start, dim3(32, 8), 0, stream>>>(wa);
    }
    cvtmem_k<<<2048, 256, 0, stream>>>(memory, cat);
    padcvt_k<<<2048, 256, 0, stream>>>(inp, inpb);
    bcat_k<<<18, 256, 0, stream>>>(bq, bkx, bvx, bqkv, 256, 256, 256, 6);
    bcat_k<<<12, 256, 0, stream>>>(bkh, bvh, bvh, bkhvh, 256, 256, 0, 6);

#define GEMM(RELU, BIAS, ACC, OUTBF, A, lda, Bt, ldb, bias_, Cf, Cb, N, K, ldc, sc) \
    gemm64<RELU, BIAS, ACC, OUTBF><<<dim3(((N) + 63) / 64, MROWS / 64), 256, 0, stream>>>( \
        A, lda, Bt, ldb, bias_, Cf, Cb, N, K, ldc, sc)
#define LNGEMM(RELU, OUTBF, X_, Bt, g_, b_, bias_, Cf, Cb, N, ldc, eps) \
    lngemm64<RELU, OUTBF><<<dim3(((N) + 63) / 64, MROWS / 64), 256, 0, stream>>>( \
        X_, Bt, g_, b_, bias_, Cf, Cb, N, ldc, eps)

    // ---- prenet: h0 -> h1 -> fc writes cat cols 512..767 ----
    GEMM(1, 1, 0, 1, inpb, 128, w0t, 128, prenet_b0, nullptr, h0b, 256, 128, 256, 1.0f);
    GEMM(1, 1, 0, 1, h0b, 256, w1pt, 256, prenet_b1, nullptr, h1b, 256, 256, 256, 1.0f);
    GEMM(0, 1, 0, 1, h1b, 256, fct, 256, prenet_fcb, nullptr, cat + 512, 256, 256, 768, 1.0f);

    // ---- in_proj: x = (cat @ W + b) * 16 ----
    GEMM(0, 1, 0, 0, cat, 768, ipjt, 768, in_proj_b, x, nullptr, 256, 768, 256, 16.0f);

    // ---- all 6 layers' kh|vh in one GEMM: [4096][3072] ----
    GEMM(0, 1, 0, 1, cat, 768, khvht, 512, bkhvh, nullptr, khvh_all, 3072, 512, 3072, 1.0f);

    // ---- layers ----
    for (int l = 0; l < 6; l++) {
        const size_t bs = (size_t)l * 256;

        LNGEMM(0, 1, x, qkvt + (size_t)l * 196608, ln1_g + bs, ln1_b + bs,
               bqkv + (size_t)l * 768, nullptr, qkv, 768, 768, 1e-5f);

        attn_mfma_k<<<dim3(TSEQ / 16, NHEAD, 4), 64, 0, stream>>>(
            qkv, khvh_all + (size_t)l * 512, 3072, ob, xbw, hbw);

        GEMM(0, 1, 1, 0, ob, 256, wot + (size_t)l * 65536, 256, bo + bs, x, nullptr,
             256, 256, 256, 1.0f);

        LNGEMM(1, 1, x, w1t + (size_t)l * 262144, ln2_g + bs, ln2_b + bs,
               b1 + (size_t)l * 1024, nullptr, f1b, 1024, 1024, 1e-5f);

        GEMM(0, 1, 1, 0, f1b, 1024, w2t + (size_t)l * 262144, 1024, b2 + bs, x, nullptr,
             256, 1024, 256, 1.0f);
    }

    // ---- final fused LN + out proj (fp32 out) ----
    LNGEMM(0, 0, x, owt, lnf_g, lnf_b, out_b, (float*)d_out, nullptr, 240, 240, 1e-6f);
#undef GEMM
#undef LNGEMM
}

// Round 10
// 596.534 us; speedup vs baseline: 1.1223x; 1.0268x over previous
//
#include <hip/hip_runtime.h>
#include <math.h>

#define MROWS 4096
#define DMODEL 256
#define NHEAD 8
#define DHEAD 32
#define TSEQ 1024
#define QKV_LD 768

typedef __bf16 bf16x8 __attribute__((ext_vector_type(8)));
typedef float f32x4 __attribute__((ext_vector_type(4)));

__device__ __forceinline__ ushort f2b(float f) {
    unsigned u = __builtin_bit_cast(unsigned, f);
    return (ushort)((u + 0x7FFFu + ((u >> 16) & 1u)) >> 16);
}

// global -> LDS direct DMA, 16 bytes per lane. LDS dest = base + lane*16.
__device__ __forceinline__ void gl16(const void* g, void* l) {
    __builtin_amdgcn_global_load_lds(
        (const __attribute__((address_space(1))) unsigned*)g,
        (__attribute__((address_space(3))) unsigned*)l, 16, 0, 0);
}

// ---------------------------------------------------------------------------
// bf16 MFMA GEMM, BM=BN=64, BK=64, 256 threads (4 waves, 32x32 quadrant each).
// Staging via global_load_lds into LINEAR LDS; XOR swizzle (chunk ^= row&7,
// 16B chunks) applied on the SOURCE address and on the frag-read address.
// C[M,N] = op(A[M,K] @ W) with W transposed: Bt[N][K]. ldc = out row stride.
// OOB B-rows (col >= N) are row-clamped; their outputs are never written.
// ---------------------------------------------------------------------------
template <int RELU, int BIAS, int ACC, int OUTBF>
__global__ __launch_bounds__(256) void gemm64(
    const ushort* __restrict__ A, int lda,
    const ushort* __restrict__ Bt, int ldb,
    const float* __restrict__ bias,
    float* __restrict__ Cf, ushort* __restrict__ Cb,
    int N, int K, int ldc, float scale)
{
    __shared__ __align__(16) ushort As[64 * 64];   // 8 KB, row stride 64 elems
    __shared__ __align__(16) ushort Bs[64 * 64];   // 8 KB
    const int t = threadIdx.x;
    const int m0 = blockIdx.y * 64;
    const int n0 = blockIdx.x * 64;
    const int w = t >> 6, lane = t & 63, lr = lane & 15, lg = lane >> 4;
    const int wm = w >> 1, wn = w & 1;

    // staging geometry: wave w, issue i covers rows i*32 + w*8 .. +7
    const int r8 = lane >> 3;           // row within 8-row group
    const int ch = lane & 7;            // dest 16B chunk within row
    const int rA0 = w * 8 + r8;         // issue-0 rows 0..31
    const int rA1 = 32 + w * 8 + r8;    // issue-1 rows 32..63
    const int cA0 = ch ^ (rA0 & 7);     // swizzled source chunk
    const int cA1 = ch ^ (rA1 & 7);

    const ushort* ag0 = A + (size_t)(m0 + rA0) * lda + cA0 * 8;
    const ushort* ag1 = A + (size_t)(m0 + rA1) * lda + cA1 * 8;
    const ushort* bg0 = Bt + (size_t)min(n0 + rA0, N - 1) * ldb + cA0 * 8;
    const ushort* bg1 = Bt + (size_t)min(n0 + rA1, N - 1) * ldb + cA1 * 8;
    ushort* la0 = &As[(w * 8) * 64];
    ushort* la1 = &As[(32 + w * 8) * 64];
    ushort* lb0 = &Bs[(w * 8) * 64];
    ushort* lb1 = &Bs[(32 + w * 8) * 64];

    f32x4 acc[2][2] = {};
    const int rfA0 = wm * 32 + lr, rfA1 = wm * 32 + 16 + lr;
    const int rfB0 = wn * 32 + lr, rfB1 = wn * 32 + 16 + lr;

    for (int k0 = 0; k0 < K; k0 += 64) {
        if (k0) __syncthreads();                 // prev reads done before overwrite
        gl16(ag0 + k0, la0);
        gl16(ag1 + k0, la1);
        gl16(bg0 + k0, lb0);
        gl16(bg1 + k0, lb1);
        __syncthreads();                         // drains vmcnt + lgkm
#pragma unroll
        for (int kh = 0; kh < 2; kh++) {
            const int cc = kh * 4 + lg;
            const bf16x8 af0 = *(const bf16x8*)&As[rfA0 * 64 + ((cc ^ (rfA0 & 7)) << 3)];
            const bf16x8 af1 = *(const bf16x8*)&As[rfA1 * 64 + ((cc ^ (rfA1 & 7)) << 3)];
            const bf16x8 bf0 = *(const bf16x8*)&Bs[rfB0 * 64 + ((cc ^ (rfB0 & 7)) << 3)];
            const bf16x8 bf1 = *(const bf16x8*)&Bs[rfB1 * 64 + ((cc ^ (rfB1 & 7)) << 3)];
            acc[0][0] = __builtin_amdgcn_mfma_f32_16x16x32_bf16(af0, bf0, acc[0][0], 0, 0, 0);
            acc[0][1] = __builtin_amdgcn_mfma_f32_16x16x32_bf16(af0, bf1, acc[0][1], 0, 0, 0);
            acc[1][0] = __builtin_amdgcn_mfma_f32_16x16x32_bf16(af1, bf0, acc[1][0], 0, 0, 0);
            acc[1][1] = __builtin_amdgcn_mfma_f32_16x16x32_bf16(af1, bf1, acc[1][1], 0, 0, 0);
        }
    }

#pragma unroll
    for (int mf = 0; mf < 2; mf++) {
        const int row = m0 + wm * 32 + mf * 16 + lg * 4;
#pragma unroll
        for (int nf = 0; nf < 2; nf++) {
            const int col = n0 + wn * 32 + nf * 16 + lr;
            if (col < N) {
                const float bb = BIAS ? bias[col] : 0.0f;
#pragma unroll
                for (int rr = 0; rr < 4; rr++) {
                    float val = acc[mf][nf][rr] + bb;
                    if (RELU) val = fmaxf(val, 0.0f);
                    const size_t idx = (size_t)(row + rr) * ldc + col;
                    if (ACC) val += Cf[idx];
                    val *= scale;
                    if (OUTBF) Cb[idx] = f2b(val);
                    else       Cf[idx] = val;
                }
            }
        }
    }
}

// ---------------------------------------------------------------------------
// Fused LayerNorm + GEMM, K=256 fixed, BM=BN=64, 256 threads.
// B tile: 8 swizzled global_load_lds issues (launched FIRST, latency hides
// under LN compute) into linear [64][256] LDS. A: LN result ds_written to a
// padded [64][264] tile. One barrier; 32 MFMAs/wave.
// ---------------------------------------------------------------------------
template <int RELU, int OUTBF>
__global__ __launch_bounds__(256) void lngemm64(
    const float* __restrict__ X,
    const ushort* __restrict__ Bt,
    const float* __restrict__ g, const float* __restrict__ bvec,
    const float* __restrict__ bias,
    float* __restrict__ Cf, ushort* __restrict__ Cb,
    int N, int ldc, float eps)
{
    __shared__ __align__(16) ushort As[64][264];   // padded, ds_write staged
    __shared__ __align__(16) ushort Bs[64 * 256];  // linear, DMA staged, 32 KB
    const int t = threadIdx.x;
    const int m0 = blockIdx.y * 64;
    const int n0 = blockIdx.x * 64;
    const int w = t >> 6, lane = t & 63;

    // ---- issue all 8 B-tile DMA loads up front ----
    {
        const int rloc = lane >> 5;         // 0/1 (row within wave's 2-row span)
        const int bch = lane & 31;          // dest 16B chunk (32 per 512B row)
#pragma unroll
        for (int is = 0; is < 8; is++) {
            const int row = is * 8 + w * 2 + rloc;
            const int brow = min(n0 + row, N - 1);
            const int c = bch ^ (row & 7);
            gl16(&Bt[(size_t)brow * 256 + c * 8], &Bs[(is * 8 + w * 2) * 256]);
        }
    }

    // ---- LN: row r, 4 lanes (q), 16 float4s each ----
    {
        const int r = t >> 2, q = t & 3;
        const float* xr = X + (size_t)(m0 + r) * 256;
        float4 v[16];
#pragma unroll
        for (int j = 0; j < 16; j++) v[j] = *(const float4*)(xr + j * 16 + q * 4);
        float sum = 0.f;
#pragma unroll
        for (int j = 0; j < 16; j++) sum += v[j].x + v[j].y + v[j].z + v[j].w;
        sum += __shfl_xor(sum, 1); sum += __shfl_xor(sum, 2);
        const float mean = sum * (1.0f / 256.0f);
        float s2 = 0.f;
#pragma unroll
        for (int j = 0; j < 16; j++) {
            v[j].x -= mean; v[j].y -= mean; v[j].z -= mean; v[j].w -= mean;
            s2 += v[j].x * v[j].x + v[j].y * v[j].y + v[j].z * v[j].z + v[j].w * v[j].w;
        }
        s2 += __shfl_xor(s2, 1); s2 += __shfl_xor(s2, 2);
        const float rstd = rsqrtf(s2 * (1.0f / 256.0f) + eps);
#pragma unroll
        for (int j = 0; j < 16; j++) {
            const float4 gv = *(const float4*)(g + j * 16 + q * 4);
            const float4 bb = *(const float4*)(bvec + j * 16 + q * 4);
            ushort4 y;
            y.x = f2b(v[j].x * rstd * gv.x + bb.x);
            y.y = f2b(v[j].y * rstd * gv.y + bb.y);
            y.z = f2b(v[j].z * rstd * gv.z + bb.z);
            y.w = f2b(v[j].w * rstd * gv.w + bb.w);
            *(ushort4*)&As[r][j * 16 + q * 4] = y;
        }
    }
    __syncthreads();

    // ---- MFMA ----
    const int lr = lane & 15, lg = lane >> 4;
    const int wm = w >> 1, wn = w & 1;
    const int rB0 = wn * 32 + lr, rB1 = wn * 32 + 16 + lr;
    f32x4 acc[2][2] = {};
#pragma unroll
    for (int ks = 0; ks < 8; ks++) {
        const int cc = ks * 4 + lg;
        const bf16x8 af0 = *(const bf16x8*)&As[wm * 32 + lr][ks * 32 + lg * 8];
        const bf16x8 af1 = *(const bf16x8*)&As[wm * 32 + 16 + lr][ks * 32 + lg * 8];
        const bf16x8 bf0 = *(const bf16x8*)&Bs[rB0 * 256 + ((cc ^ (rB0 & 7)) << 3)];
        const bf16x8 bf1 = *(const bf16x8*)&Bs[rB1 * 256 + ((cc ^ (rB1 & 7)) << 3)];
        acc[0][0] = __builtin_amdgcn_mfma_f32_16x16x32_bf16(af0, bf0, acc[0][0], 0, 0, 0);
        acc[0][1] = __builtin_amdgcn_mfma_f32_16x16x32_bf16(af0, bf1, acc[0][1], 0, 0, 0);
        acc[1][0] = __builtin_amdgcn_mfma_f32_16x16x32_bf16(af1, bf0, acc[1][0], 0, 0, 0);
        acc[1][1] = __builtin_amdgcn_mfma_f32_16x16x32_bf16(af1, bf1, acc[1][1], 0, 0, 0);
    }

#pragma unroll
    for (int mf = 0; mf < 2; mf++) {
        const int row = m0 + wm * 32 + mf * 16 + lg * 4;
#pragma unroll
        for (int nf = 0; nf < 2; nf++) {
            const int col = n0 + wn * 32 + nf * 16 + lr;
            if (col < N) {
                const float bb = bias[col];
#pragma unroll
                for (int rr = 0; rr < 4; rr++) {
                    float val = acc[mf][nf][rr] + bb;
                    if (RELU) val = fmaxf(val, 0.0f);
                    const size_t idx = (size_t)(row + rr) * ldc + col;
                    if (OUTBF) Cb[idx] = f2b(val);
                    else       Cf[idx] = val;
                }
            }
        }
    }
}

// ---------------------------------------------------------------------------
// MFMA dual banded attention (verified structure; khvh strided).
// ---------------------------------------------------------------------------
__global__ __launch_bounds__(64) void attn_mfma_k(
    const ushort* __restrict__ qkv, const ushort* __restrict__ khvh, int kld,
    ushort* __restrict__ o,
    const int* __restrict__ xbw_p, const int* __restrict__ hbw_p)
{
    __shared__ __align__(16) ushort Vt[32][40];

    const int l = threadIdx.x;
    const int c = l & 15;
    const int g = l >> 4;
    const int i0 = blockIdx.x * 16;
    const int h  = blockIdx.y;
    const int rowb = blockIdx.z * TSEQ;
    const int i = i0 + c;
    const int xbw = min(xbw_p[0], 64);
    const int hbw = min(hbw_p[0], 48);
    const float scale = 0.17677669529663687f;
    const f32x4 fz = {0.0f, 0.0f, 0.0f, 0.0f};

    const bf16x8 qf = *(const bf16x8*)(qkv + (size_t)(rowb + i) * QKV_LD + h * DHEAD + g * 8);

    f32x4 sx[5], sh[4];
#pragma unroll
    for (int t = 0; t < 5; t++) {
        int kr = i0 - 64 + t * 16 + c;
        kr = min(max(kr, 0), TSEQ - 1);
        const bf16x8 kf = *(const bf16x8*)(qkv + (size_t)(rowb + kr) * QKV_LD + 256 + h * DHEAD + g * 8);
        sx[t] = __builtin_amdgcn_mfma_f32_16x16x32_bf16(kf, qf, fz, 0, 0, 0);
    }
#pragma unroll
    for (int t = 0; t < 4; t++) {
        int kr = i0 + t * 16 + c;
        kr = min(kr, TSEQ - 1);
        const bf16x8 kf = *(const bf16x8*)(khvh + (size_t)(rowb + kr) * kld + h * DHEAD + g * 8);
        sh[t] = __builtin_amdgcn_mfma_f32_16x16x32_bf16(kf, qf, fz, 0, 0, 0);
    }

    const float NEG = -3.0e38f;
    float mx = NEG, mh = NEG;
#pragma unroll
    for (int t = 0; t < 5; t++)
#pragma unroll
        for (int r = 0; r < 4; r++) {
            const int j = i0 - 64 + t * 16 + g * 4 + r;
            const bool v = (j >= i - xbw) & (j <= i) & (j >= 0);
            sx[t][r] = v ? sx[t][r] : NEG;
            mx = fmaxf(mx, sx[t][r]);
        }
#pragma unroll
    for (int t = 0; t < 4; t++)
#pragma unroll
        for (int r = 0; r < 4; r++) {
            const int j = i0 + t * 16 + g * 4 + r;
            const int dj = j - i;
            const bool v = (dj >= 0) & (dj <= hbw) & (j <= TSEQ - 1);
            sh[t][r] = v ? sh[t][r] : NEG;
            mh = fmaxf(mh, sh[t][r]);
        }
    mx = fmaxf(mx, __shfl_xor(mx, 16)); mx = fmaxf(mx, __shfl_xor(mx, 32));
    mh = fmaxf(mh, __shfl_xor(mh, 16)); mh = fmaxf(mh, __shfl_xor(mh, 32));

    float sumx = 0.0f, sumh = 0.0f;
#pragma unroll
    for (int t = 0; t < 5; t++)
#pragma unroll
        for (int r = 0; r < 4; r++) { const float e = __expf((sx[t][r] - mx) * scale); sx[t][r] = e; sumx += e; }
#pragma unroll
    for (int t = 0; t < 4; t++)
#pragma unroll
        for (int r = 0; r < 4; r++) { const float e = __expf((sh[t][r] - mh) * scale); sh[t][r] = e; sumh += e; }
    sumx += __shfl_xor(sumx, 16); sumx += __shfl_xor(sumx, 32);
    sumh += __shfl_xor(sumh, 16); sumh += __shfl_xor(sumh, 32);
    const float invx = 1.0f / sumx;
    const float invh = 1.0f / sumh;

    unsigned pkx[6][2], pkh[4][2];
#pragma unroll
    for (int t = 0; t < 5; t++) {
        pkx[t][0] = (unsigned)f2b(sx[t][0] * invx) | ((unsigned)f2b(sx[t][1] * invx) << 16);
        pkx[t][1] = (unsigned)f2b(sx[t][2] * invx) | ((unsigned)f2b(sx[t][3] * invx) << 16);
    }
    pkx[5][0] = 0; pkx[5][1] = 0;
#pragma unroll
    for (int t = 0; t < 4; t++) {
        pkh[t][0] = (unsigned)f2b(sh[t][0] * invh) | ((unsigned)f2b(sh[t][1] * invh) << 16);
        pkh[t][1] = (unsigned)f2b(sh[t][2] * invh) | ((unsigned)f2b(sh[t][3] * invh) << 16);
    }

    f32x4 acc0 = fz, acc1 = fz;
    const int src0 = ((l >> 4) & 1) * 32 + c;
    const int src1 = src0 + 16;
    const bool hiT = (g >= 2);

    const int jq  = l >> 2;
    const int dq  = l & 3;
    const int dcol = dq * 8;
    const int col1 = ((((l >> 5) + 0) ^ dq) << 3) | (jq & 7);
    const int col2 = ((((l >> 5) + 2) ^ dq) << 3) | (jq & 7);
    const int rb0 = ((g ^ ((c) >> 3)) << 3);
    const int rb1 = ((g ^ (2 + (c >> 3))) << 3);

#define PV_CHUNK(VBASE, VLD, JB, PA0, PA1, PB0, PB1)                                   \
    {                                                                                   \
        int r1 = min(max((JB) + jq, 0), TSEQ - 1);                                      \
        int r2 = min(max((JB) + 16 + jq, 0), TSEQ - 1);                                 \
        const int4 v1 = *(const int4*)((VBASE) + (size_t)(rowb + r1) * (VLD) + dcol);   \
        const int4 v2 = *(const int4*)((VBASE) + (size_t)(rowb + r2) * (VLD) + dcol);   \
        __syncthreads();                                                                \
        const ushort* u1 = (const ushort*)&v1;                                          \
        const ushort* u2 = (const ushort*)&v2;                                          \
        _Pragma("unroll")                                                               \
        for (int e = 0; e < 8; e++) { Vt[dcol + e][col1] = u1[e]; Vt[dcol + e][col2] = u2[e]; } \
        const unsigned xA0 = __shfl((int)(PA0), src0), xA1 = __shfl((int)(PA1), src0);  \
        const unsigned xA2 = __shfl((int)(PA0), src1), xA3 = __shfl((int)(PA1), src1);  \
        const unsigned xB0 = __shfl((int)(PB0), src0), xB1 = __shfl((int)(PB1), src0);  \
        const unsigned xB2 = __shfl((int)(PB0), src1), xB3 = __shfl((int)(PB1), src1);  \
        int4 au;                                                                        \
        au.x = (int)(hiT ? xB0 : xA0); au.y = (int)(hiT ? xB1 : xA1);                   \
        au.z = (int)(hiT ? xB2 : xA2); au.w = (int)(hiT ? xB3 : xA3);                   \
        const bf16x8 pf = __builtin_bit_cast(bf16x8, au);                               \
        __syncthreads();                                                                \
        const bf16x8 vf0 = *(const bf16x8*)&Vt[c][rb0];                                 \
        const bf16x8 vf1 = *(const bf16x8*)&Vt[16 + c][rb1];                            \
        acc0 = __builtin_amdgcn_mfma_f32_16x16x32_bf16(pf, vf0, acc0, 0, 0, 0);         \
        acc1 = __builtin_amdgcn_mfma_f32_16x16x32_bf16(pf, vf1, acc1, 0, 0, 0);         \
    }

    const ushort* vx = qkv + 512 + h * DHEAD;
    const ushort* vh = khvh + 256 + h * DHEAD;
    PV_CHUNK(vx, QKV_LD, i0 - 64, pkx[0][0], pkx[0][1], pkx[1][0], pkx[1][1]);
    PV_CHUNK(vx, QKV_LD, i0 - 32, pkx[2][0], pkx[2][1], pkx[3][0], pkx[3][1]);
    PV_CHUNK(vx, QKV_LD, i0,      pkx[4][0], pkx[4][1], pkx[5][0], pkx[5][1]);
    PV_CHUNK(vh, kld,    i0,      pkh[0][0], pkh[0][1], pkh[1][0], pkh[1][1]);
    PV_CHUNK(vh, kld,    i0 + 32, pkh[2][0], pkh[2][1], pkh[3][0], pkh[3][1]);
#undef PV_CHUNK

#pragma unroll
    for (int r = 0; r < 4; r++) {
        const size_t row = (size_t)(rowb + i0 + g * 4 + r) * DMODEL + h * DHEAD;
        o[row + c]      = f2b(acc0[r]);
        o[row + 16 + c] = f2b(acc1[r]);
    }
}

// ---------------------------------------------------------------------------
// Mega weight convert+transpose: 13 segments, one launch.
// ---------------------------------------------------------------------------
struct WSeg {
    const float* src; ushort* dst;
    long sstride, dstride;
    int K, N, Kd, tx, tpl, start;
};
struct WcvtArgs { WSeg s[13]; };

__global__ void wcvt_k(WcvtArgs a)
{
    const int bid = blockIdx.x;
    int si = 0;
#pragma unroll
    for (int i = 1; i < 13; i++) if (bid >= a.s[i].start) si = i;
    const WSeg sg = a.s[si];
    const int lt = bid - sg.start;
    const int l = lt / sg.tpl, rem = lt % sg.tpl;
    const int k0 = (rem / sg.tx) * 32, n0 = (rem % sg.tx) * 32;
    const float* src = sg.src + (size_t)l * sg.sstride;
    ushort* dst = sg.dst + (size_t)l * sg.dstride;

    __shared__ float tbuf[32][33];
    const int tx = threadIdx.x, ty = threadIdx.y;
#pragma unroll
    for (int r = 0; r < 4; r++) {
        const int k = k0 + ty + r * 8, n = n0 + tx;
        tbuf[ty + r * 8][tx] = (k < sg.K && n < sg.N) ? src[(size_t)k * sg.N + n] : 0.0f;
    }
    __syncthreads();
#pragma unroll
    for (int r = 0; r < 4; r++) {
        const int n = n0 + ty + r * 8, k = k0 + tx;
        if (n < sg.N && k < sg.Kd) dst[(size_t)n * sg.Kd + k] = f2b(tbuf[tx][ty + r * 8]);
    }
}

// ---------------------------------------------------------------------------
// Small conversions
// ---------------------------------------------------------------------------
__global__ void cvtmem_k(const float* __restrict__ s, ushort* __restrict__ cat)
{
    const int i = blockIdx.x * 256 + threadIdx.x;   // 4096*128
    const int row = i >> 7, c4 = (i & 127) * 4;
    const float4 v = *(const float4*)(s + (size_t)row * 512 + c4);
    ushort4 o;
    o.x = f2b(v.x); o.y = f2b(v.y); o.z = f2b(v.z); o.w = f2b(v.w);
    *(ushort4*)(cat + (size_t)row * 768 + c4) = o;
}

__global__ void padcvt_k(const float* __restrict__ s, ushort* __restrict__ d)
{
    const int i = blockIdx.x * 256 + threadIdx.x;   // 4096*128
    const int r = i >> 7, c = i & 127;
    d[i] = (c < 80) ? f2b(s[r * 80 + c]) : (ushort)0;
}

__global__ void bcat_k(const float* __restrict__ a, const float* __restrict__ b,
                       const float* __restrict__ c, float* __restrict__ dst,
                       int na, int nb, int nc, int L)
{
    const int per = na + nb + nc;
    const int i = blockIdx.x * 256 + threadIdx.x;
    if (i >= per * L) return;
    const int l = i / per, r = i % per;
    float v;
    if (r < na) v = a[l * na + r];
    else if (r < na + nb) v = b[l * nb + (r - na)];
    else v = c[l * nc + (r - na - nb)];
    dst[i] = v;
}

// ---------------------------------------------------------------------------
// Launch
// ---------------------------------------------------------------------------
extern "C" void kernel_launch(void* const* d_in, const int* in_sizes, int n_in,
                              void* d_out, int out_size, void* d_ws, size_t ws_size,
                              hipStream_t stream)
{
    const float* inp        = (const float*)d_in[0];
    const float* memory     = (const float*)d_in[1];
    const int*   xbw        = (const int*)d_in[2];
    const int*   hbw        = (const int*)d_in[3];
    const float* prenet_w0  = (const float*)d_in[5];
    const float* prenet_b0  = (const float*)d_in[6];
    const float* prenet_w1  = (const float*)d_in[7];
    const float* prenet_b1  = (const float*)d_in[8];
    const float* prenet_fcw = (const float*)d_in[9];
    const float* prenet_fcb = (const float*)d_in[10];
    const float* in_proj_w  = (const float*)d_in[11];
    const float* in_proj_b  = (const float*)d_in[12];
    const float* ln1_g      = (const float*)d_in[13];
    const float* ln1_b      = (const float*)d_in[14];
    const float* wq         = (const float*)d_in[15];
    const float* bq         = (const float*)d_in[16];
    const float* wkx        = (const float*)d_in[17];
    const float* bkx        = (const float*)d_in[18];
    const float* wvx        = (const float*)d_in[19];
    const float* bvx        = (const float*)d_in[20];
    const float* wkh        = (const float*)d_in[21];
    const float* bkh        = (const float*)d_in[22];
    const float* wvh        = (const float*)d_in[23];
    const float* bvh        = (const float*)d_in[24];
    const float* wo         = (const float*)d_in[25];
    const float* bo         = (const float*)d_in[26];
    const float* ln2_g      = (const float*)d_in[27];
    const float* ln2_b      = (const float*)d_in[28];
    const float* w1         = (const float*)d_in[29];
    const float* b1         = (const float*)d_in[30];
    const float* w2         = (const float*)d_in[31];
    const float* b2         = (const float*)d_in[32];
    const float* lnf_g      = (const float*)d_in[33];
    const float* lnf_b      = (const float*)d_in[34];
    const float* out_w      = (const float*)d_in[35];
    const float* out_b      = (const float*)d_in[36];

    char* base = (char*)d_ws;
    const size_t MB = 1u << 20;
    float*  x        = (float*)(base);                 //  0: 4 MiB fp32 residual
    ushort* cat      = (ushort*)(base + 4 * MB);       //  4: 6 MiB [4096][768] = mem|h
    ushort* qkv      = (ushort*)(base + 10 * MB);      // 10: 6 MiB [4096][768]
    ushort* ob       = (ushort*)(base + 16 * MB);      // 16: 2 MiB
    ushort* f1b      = (ushort*)(base + 18 * MB);      // 18: 8 MiB [4096][1024]
    ushort* khvh_all = (ushort*)(base + 26 * MB);      // 26: 24 MiB [4096][3072]
    ushort* h0b      = (ushort*)(base + 50 * MB);      // 50: 2 MiB
    ushort* h1b      = (ushort*)(base + 52 * MB);      // 52: 2 MiB
    ushort* inpb     = (ushort*)(base + 54 * MB);      // 54: 1 MiB [4096][128]

    size_t off = 56 * MB;
    ushort* w0t   = (ushort*)(base + off); off += (size_t)256 * 128 * 2;
    ushort* w1pt  = (ushort*)(base + off); off += (size_t)256 * 256 * 2;
    ushort* fct   = (ushort*)(base + off); off += (size_t)256 * 256 * 2;
    ushort* ipjt  = (ushort*)(base + off); off += (size_t)256 * 768 * 2;
    ushort* qkvt  = (ushort*)(base + off); off += (size_t)6 * 768 * 256 * 2;
    ushort* khvht = (ushort*)(base + off); off += (size_t)6 * 512 * 512 * 2;   // [3072][512]
    ushort* wot   = (ushort*)(base + off); off += (size_t)6 * 256 * 256 * 2;
    ushort* w1t   = (ushort*)(base + off); off += (size_t)6 * 1024 * 256 * 2;
    ushort* w2t   = (ushort*)(base + off); off += (size_t)6 * 256 * 1024 * 2;
    ushort* owt   = (ushort*)(base + off); off += (size_t)240 * 256 * 2;
    float*  bqkv  = (float*)(base + off);  off += (size_t)6 * 768 * 4;
    float*  bkhvh = (float*)(base + off);  off += (size_t)6 * 512 * 4;

    // ---- one-launch weight conversion ----
    WcvtArgs wa;
    {
        auto seg = [](const float* src, ushort* dst, int K, int N, int Kd,
                      long ss, long ds) {
            WSeg s; s.src = src; s.dst = dst; s.K = K; s.N = N; s.Kd = Kd;
            s.sstride = ss; s.dstride = ds;
            s.tx = (N + 31) / 32;
            s.tpl = s.tx * ((Kd + 31) / 32);
            s.start = 0; return s;
        };
        wa.s[0]  = seg(prenet_w0, w0t,  80,  256, 128, 0, 0);
        wa.s[1]  = seg(prenet_w1, w1pt, 256, 256, 256, 0, 0);
        wa.s[2]  = seg(prenet_fcw, fct, 256, 256, 256, 0, 0);
        wa.s[3]  = seg(in_proj_w, ipjt, 768, 256, 768, 0, 0);
        wa.s[4]  = seg(wq,  qkvt,           256, 256,  256, 65536, 196608);
        wa.s[5]  = seg(wkx, qkvt + 65536,   256, 256,  256, 65536, 196608);
        wa.s[6]  = seg(wvx, qkvt + 131072,  256, 256,  256, 65536, 196608);
        wa.s[7]  = seg(wkh, khvht,          512, 256,  512, 131072, 262144);
        wa.s[8]  = seg(wvh, khvht + 131072, 512, 256,  512, 131072, 262144);
        wa.s[9]  = seg(wo,  wot,            256, 256,  256, 65536, 65536);
        wa.s[10] = seg(w1,  w1t,            256, 1024, 256, 262144, 262144);
        wa.s[11] = seg(w2,  w2t,            1024, 256, 1024, 262144, 262144);
        wa.s[12] = seg(out_w, owt,          256, 240,  256, 0, 0);
        const int Ls[13] = {1,1,1,1,6,6,6,6,6,6,6,6,1};
        int start = 0;
        for (int i = 0; i < 13; i++) {
            wa.s[i].start = start;
            start += wa.s[i].tpl * Ls[i];
        }
        wcvt_k<<<start, dim3(32, 8), 0, stream>>>(wa);
    }
    cvtmem_k<<<2048, 256, 0, stream>>>(memory, cat);
    padcvt_k<<<2048, 256, 0, stream>>>(inp, inpb);
    bcat_k<<<18, 256, 0, stream>>>(bq, bkx, bvx, bqkv, 256, 256, 256, 6);
    bcat_k<<<12, 256, 0, stream>>>(bkh, bvh, bvh, bkhvh, 256, 256, 0, 6);

#define GEMM(RELU, BIAS, ACC, OUTBF, A, lda, Bt, ldb, bias_, Cf, Cb, N, K, ldc, sc) \
    gemm64<RELU, BIAS, ACC, OUTBF><<<dim3(((N) + 63) / 64, MROWS / 64), 256, 0, stream>>>( \
        A, lda, Bt, ldb, bias_, Cf, Cb, N, K, ldc, sc)
#define LNGEMM(RELU, OUTBF, X_, Bt, g_, b_, bias_, Cf, Cb, N, ldc, eps) \
    lngemm64<RELU, OUTBF><<<dim3(((N) + 63) / 64, MROWS / 64), 256, 0, stream>>>( \
        X_, Bt, g_, b_, bias_, Cf, Cb, N, ldc, eps)

    // ---- prenet: h0 -> h1 -> fc writes cat cols 512..767 ----
    GEMM(1, 1, 0, 1, inpb, 128, w0t, 128, prenet_b0, nullptr, h0b, 256, 128, 256, 1.0f);
    GEMM(1, 1, 0, 1, h0b, 256, w1pt, 256, prenet_b1, nullptr, h1b, 256, 256, 256, 1.0f);
    GEMM(0, 1, 0, 1, h1b, 256, fct, 256, prenet_fcb, nullptr, cat + 512, 256, 256, 768, 1.0f);

    // ---- in_proj: x = (cat @ W + b) * 16 ----
    GEMM(0, 1, 0, 0, cat, 768, ipjt, 768, in_proj_b, x, nullptr, 256, 768, 256, 16.0f);

    // ---- all 6 layers' kh|vh in one GEMM: [4096][3072] ----
    GEMM(0, 1, 0, 1, cat, 768, khvht, 512, bkhvh, nullptr, khvh_all, 3072, 512, 3072, 1.0f);

    // ---- layers ----
    for (int l = 0; l < 6; l++) {
        const size_t bs = (size_t)l * 256;

        LNGEMM(0, 1, x, qkvt + (size_t)l * 196608, ln1_g + bs, ln1_b + bs,
               bqkv + (size_t)l * 768, nullptr, qkv, 768, 768, 1e-5f);

        attn_mfma_k<<<dim3(TSEQ / 16, NHEAD, 4), 64, 0, stream>>>(
            qkv, khvh_all + (size_t)l * 512, 3072, ob, xbw, hbw);

        GEMM(0, 1, 1, 0, ob, 256, wot + (size_t)l * 65536, 256, bo + bs, x, nullptr,
             256, 256, 256, 1.0f);

        LNGEMM(1, 1, x, w1t + (size_t)l * 262144, ln2_g + bs, ln2_b + bs,
               b1 + (size_t)l * 1024, nullptr, f1b, 1024, 1024, 1e-5f);

        GEMM(0, 1, 1, 0, f1b, 1024, w2t + (size_t)l * 262144, 1024, b2 + bs, x, nullptr,
             256, 1024, 256, 1.0f);
    }

    // ---- final fused LN + out proj (fp32 out) ----
    LNGEMM(0, 0, x, owt, lnf_g, lnf_b, out_b, (float*)d_out, nullptr, 240, 240, 1e-6f);
#undef GEMM
#undef LNGEMM
}